// Round 4
// baseline (13258.817 us; speedup 1.0000x reference)
//
#include <hip/hip_runtime.h>
#include <cstdint>
#include <cstddef>

using u16 = unsigned short;
typedef __attribute__((ext_vector_type(8))) short short8;
typedef __attribute__((ext_vector_type(4))) float f32x4;

__device__ __forceinline__ float bf2f(u16 u) {
  unsigned int i = ((unsigned int)u) << 16;
  float f; __builtin_memcpy(&f, &i, 4); return f;
}
__device__ __forceinline__ u16 f2bf(float f) {
  unsigned int i; __builtin_memcpy(&i, &f, 4);
  unsigned int r = (i + 0x7FFFu + ((i >> 16) & 1u)) >> 16;
  return (u16)r;
}
__device__ __forceinline__ float sigm_f(float x) { return 1.f / (1.f + __expf(-x)); }
__device__ __forceinline__ float tanh_f(float x) {
  float cx = fminf(10.f, fmaxf(-10.f, x));
  float e = __expf(2.f * cx);
  return (e - 1.f) / (e + 1.f);
}

// ---------------- prep kernels ----------------
// W_ih (2048x512) -> Wihcat (2048x1536) bf16 = [hi | hi | lo]
__global__ void wih_prep_kernel(const float* __restrict__ W, u16* __restrict__ dst) {
  int i = blockIdx.x * 256 + threadIdx.x;  // 2048*1536
  int r = i / 1536, k = i - r * 1536;
  u16 v;
  if (k < 1024) {
    int kk = (k < 512) ? k : (k - 512);
    v = f2bf(W[(size_t)r * 512 + kk]);
  } else {
    float x = W[(size_t)r * 512 + (k - 1024)];
    u16 hi = f2bf(x);
    v = f2bf(x - bf2f(hi));
  }
  dst[i] = v;
}

// W_hh (2048x512) -> Whhcat (2048x1024) bf16 = [hi | lo]
__global__ void whh_prep_kernel(const float* __restrict__ W, u16* __restrict__ dst) {
  int i = blockIdx.x * 256 + threadIdx.x;  // 2048*1024
  int r = i >> 10, k = i & 1023;
  u16 v;
  if (k < 512) v = f2bf(W[(size_t)r * 512 + k]);
  else {
    float x = W[(size_t)r * 512 + (k - 512)];
    u16 hi = f2bf(x);
    v = f2bf(x - bf2f(hi));
  }
  dst[i] = v;
}

// mlp_W (80x512) -> Mlpcat (128x1536) bf16 = [Whi | Whi | Wlo], rows>=80 zero
__global__ void mlp_prep_kernel(const float* __restrict__ mlpW, u16* __restrict__ dst) {
  int i = blockIdx.x * 256 + threadIdx.x;  // 128*1536
  int r = i / 1536, k = i - r * 1536;
  u16 v = 0;
  if (r < 80) {
    if (k < 1024) {
      int kk = (k < 512) ? k : (k - 512);
      v = f2bf(mlpW[r * 512 + kk]);
    } else {
      float x = mlpW[r * 512 + (k - 1024)];
      u16 hi = f2bf(x);
      v = f2bf(x - bf2f(hi));
    }
  }
  dst[i] = v;
}

// fc_W (1000x1024) -> Wcat (1024 x 3072) bf16 = [Whi | Whi | Wlo], rows >=1000 zero
__global__ void fc_prep_kernel(const float* __restrict__ fcW, u16* __restrict__ dst) {
  int i = blockIdx.x * 256 + threadIdx.x;  // 1024*3072
  int n = i / 3072, k = i - n * 3072;
  u16 v = 0;
  if (n < 1000) {
    if (k < 2048) {
      int kk = (k < 1024) ? k : (k - 1024);
      v = f2bf(fcW[(size_t)n * 1024 + kk]);
    } else {
      float x = fcW[(size_t)n * 1024 + (k - 2048)];
      u16 hi = f2bf(x);
      v = f2bf(x - bf2f(hi));
    }
  }
  dst[i] = v;
}

// embeddings -> saecat split bf16 (32768 x 1024) = [sae_hi(512) | sae_lo(512)]
__global__ void embed_kernel(const int* __restrict__ skill, const int* __restrict__ answer,
                             const float* __restrict__ st, const float* __restrict__ at,
                             u16* __restrict__ saecat) {
  int r = blockIdx.x;
  int s = skill[r], a = answer[r];
  const float* se = st + (size_t)s * 256;
  const float* ae = at + (size_t)a * 256;
  u16* dst = saecat + (size_t)r * 1024;
  int c = threadIdx.x;  // 0..255
  bool one = (a == 1);
  float v0 = one ? se[c] : ae[c];
  float v1 = one ? ae[c] : se[c];
  u16 h0 = f2bf(v0), h1 = f2bf(v1);
  dst[c] = h0;
  dst[c + 256] = h1;
  dst[512 + c] = f2bf(v0 - bf2f(h0));
  dst[768 + c] = f2bf(v1 - bf2f(h1));
}

// ---------------- generic bf16 MFMA GEMM: C = A(MxK) * Bw(NxK)^T ----------------
// Virtual-K: A column = (k >= kwrap) ? k - kwrap : k  (B always reads k directly).
// MODE 0: x_pre: +(b_ih+b_hh), store FP32 x_pre[(t*32+b)*2048+col], row=(b<<10|t)
// MODE 1: att1:  store fp32 T[row*128+col]
// MODE 2: fc:    +fc_b, sigmoid, store fp32 d_out[row*1000+col] (col<1000)
template <int MODE>
__global__ __launch_bounds__(256) void gemm_bt(
    const u16* __restrict__ A, const u16* __restrict__ Bw,
    const float* __restrict__ bias0, const float* __restrict__ bias1,
    void* __restrict__ Cout, int N, int K, int lda, int ldb, int kwrap)
{
  __shared__ u16 As[128][40];
  __shared__ u16 Bs[128][40];
  const int ntn = N >> 7;
  const int tm = blockIdx.x / ntn;
  const int tn = blockIdx.x - tm * ntn;
  const int r0 = tm << 7, c0 = tn << 7;
  const int tid = threadIdx.x;
  const int lane = tid & 63, w = tid >> 6;
  const int wr = (w >> 1) << 6, wc = (w & 1) << 6;
  const int sr = tid >> 2, sk = (tid & 3) << 3;
  const int fr = lane & 15, fk = (lane >> 4) << 3;
  f32x4 zero = {0.f, 0.f, 0.f, 0.f};
  f32x4 acc[4][4];
#pragma unroll
  for (int i = 0; i < 4; i++)
#pragma unroll
    for (int j = 0; j < 4; j++) acc[i][j] = zero;

  for (int k0 = 0; k0 < K; k0 += 32) {
    int ka = (k0 >= kwrap) ? (k0 - kwrap) : k0;
    const u16* Ap = A + (size_t)(r0 + sr) * lda + ka + sk;
    const u16* Bp = Bw + (size_t)(c0 + sr) * ldb + k0 + sk;
    *(short8*)(&As[sr][sk])      = *(const short8*)(Ap);
    *(short8*)(&As[sr + 64][sk]) = *(const short8*)(Ap + (size_t)64 * lda);
    *(short8*)(&Bs[sr][sk])      = *(const short8*)(Bp);
    *(short8*)(&Bs[sr + 64][sk]) = *(const short8*)(Bp + (size_t)64 * ldb);
    __syncthreads();
    short8 af[4], bfv[4];
#pragma unroll
    for (int i = 0; i < 4; i++) af[i] = *(const short8*)(&As[wr + i * 16 + fr][fk]);
#pragma unroll
    for (int i = 0; i < 4; i++) bfv[i] = *(const short8*)(&Bs[wc + i * 16 + fr][fk]);
#pragma unroll
    for (int mi = 0; mi < 4; mi++)
#pragma unroll
      for (int ni = 0; ni < 4; ni++)
        acc[mi][ni] = __builtin_amdgcn_mfma_f32_16x16x32_bf16(af[mi], bfv[ni], acc[mi][ni], 0, 0, 0);
    __syncthreads();
  }

  const int cr = (lane >> 4) << 2, cc = lane & 15;
  if constexpr (MODE == 0) {
    float* xp = (float*)Cout;
#pragma unroll
    for (int ni = 0; ni < 4; ni++) {
      int col = c0 + wc + ni * 16 + cc;
      float bs = bias0[col] + bias1[col];
#pragma unroll
      for (int mi = 0; mi < 4; mi++)
#pragma unroll
        for (int r = 0; r < 4; r++) {
          int row = r0 + wr + mi * 16 + cr + r;
          int t = row & 1023, b = row >> 10;
          xp[(size_t)(t * 32 + b) * 2048 + col] = acc[mi][ni][r] + bs;
        }
    }
  } else if constexpr (MODE == 1) {
    float* T = (float*)Cout;
#pragma unroll
    for (int ni = 0; ni < 4; ni++) {
      int col = c0 + wc + ni * 16 + cc;
#pragma unroll
      for (int mi = 0; mi < 4; mi++)
#pragma unroll
        for (int r = 0; r < 4; r++) {
          int row = r0 + wr + mi * 16 + cr + r;
          T[(size_t)row * 128 + col] = acc[mi][ni][r];
        }
    }
  } else {
    float* op = (float*)Cout;
#pragma unroll
    for (int ni = 0; ni < 4; ni++) {
      int col = c0 + wc + ni * 16 + cc;
      if (col < 1000) {
        float bs = bias0[col];
#pragma unroll
        for (int mi = 0; mi < 4; mi++)
#pragma unroll
          for (int r = 0; r < 4; r++) {
            int row = r0 + wr + mi * 16 + cr + r;
            op[(size_t)row * 1000 + col] = sigm_f(acc[mi][ni][r] + bs);
          }
      }
    }
  }
}

// ---------------- persistent LSTM (split-bf16 h and W_hh, fp32 x_pre) ----------------
// 32 wgs x 256 thr. wg owns hidden cols [wg*16, wg*16+16). wave w = gate (i,f,g,o).
// h published as hi+lo bf16 via device double-buffer hbuf[2][2][32][512], PRE-SWIZZLED:
//   byte(b,k) = region + b*1024 + ((2k) ^ ((b&7)<<4)); lo region at +32 KiB.
// Gates use 3-term product: h_hi*W_hi + h_lo*W_hi + h_hi*W_lo.
__global__ __launch_bounds__(256) void lstm_kernel(
    const float* __restrict__ xpre, const u16* __restrict__ Whh,
    u16* __restrict__ outb, u16* __restrict__ hbuf, unsigned* __restrict__ flags)
{
  __shared__ u16 hl[32768];           // 64 KB: h(t-1) hi (32KB) + lo (32KB), swizzled
  __shared__ float gbuf[4][16][33];   // gate exchange (pad 33 -> conflict-free)
  __shared__ float cl[512];           // cell state c (fp32, resident)
  const int tid = threadIdx.x;
  const int lane = tid & 63, w = tid >> 6;
  const int wg = blockIdx.x;
  const int base = wg << 4;
  const int col = lane & 15;
  const int kofs = (lane >> 4) << 3;

  short8 whi[16], wlo[16];  // W_hh fragments (hi+lo), resident for all 1024 steps
  {
    const u16* wp = Whh + (size_t)(w * 512 + base + col) * 1024 + kofs;
#pragma unroll
    for (int kt = 0; kt < 16; kt++) {
      whi[kt] = *(const short8*)(wp + kt * 32);
      wlo[kt] = *(const short8*)(wp + 512 + kt * 32);
    }
  }
  cl[tid] = 0.f; cl[tid + 256] = 0.f;
  __syncthreads();

  for (int t = 0; t < 1024; t++) {
    // prefetch x_pre gate slice (independent of the sync)
    float xv[8];
    {
      const float* xp = xpre + (size_t)t * 32 * 2048 + (w * 512 + base + col);
#pragma unroll
      for (int mt = 0; mt < 2; mt++)
#pragma unroll
        for (int r = 0; r < 4; r++) {
          int b = (lane >> 4) * 4 + r + mt * 16;
          xv[mt * 4 + r] = xp[(size_t)b * 2048];
        }
    }
    // wait for all wgs to have published h(t-1)
    if (t > 0) {
      for (;;) {
        unsigned v = 0xFFFFFFFFu;
        if (lane < 32) v = __hip_atomic_load(&flags[lane], __ATOMIC_RELAXED, __HIP_MEMORY_SCOPE_AGENT);
        if (!(~__ballot(v >= (unsigned)t))) break;
      }
      __threadfence();  // acquire
    }
    // stage h(t-1) hi+lo to LDS (64 KB)
    {
      const short8* hs = (const short8*)(hbuf + (size_t)(t & 1) * 32768);
      short8* hd = (short8*)hl;
#pragma unroll
      for (int i = 0; i < 16; i++) hd[i * 256 + tid] = hs[i * 256 + tid];
    }
    __syncthreads();
    // gates = h @ Whh_slice^T  (M=32 batches, N=16 cols, K=512, 3-term split)
    f32x4 acc0 = {0.f,0.f,0.f,0.f}, acc1 = {0.f,0.f,0.f,0.f};
    {
      const char* hb = (const char*)hl;
#pragma unroll
      for (int kt = 0; kt < 16; kt++) {
        int kbyte = (kt * 32 + kofs) * 2;
        int b0 = col, b1 = col + 16;
        int o0 = b0 * 1024 + (kbyte ^ ((b0 & 7) << 4));
        int o1 = b1 * 1024 + (kbyte ^ ((b1 & 7) << 4));
        short8 a0 = *(const short8*)(hb + o0);
        short8 a1 = *(const short8*)(hb + o1);
        short8 l0 = *(const short8*)(hb + 32768 + o0);
        short8 l1 = *(const short8*)(hb + 32768 + o1);
        acc0 = __builtin_amdgcn_mfma_f32_16x16x32_bf16(a0, whi[kt], acc0, 0, 0, 0);
        acc1 = __builtin_amdgcn_mfma_f32_16x16x32_bf16(a1, whi[kt], acc1, 0, 0, 0);
        acc0 = __builtin_amdgcn_mfma_f32_16x16x32_bf16(l0, whi[kt], acc0, 0, 0, 0);
        acc1 = __builtin_amdgcn_mfma_f32_16x16x32_bf16(l1, whi[kt], acc1, 0, 0, 0);
        acc0 = __builtin_amdgcn_mfma_f32_16x16x32_bf16(a0, wlo[kt], acc0, 0, 0, 0);
        acc1 = __builtin_amdgcn_mfma_f32_16x16x32_bf16(a1, wlo[kt], acc1, 0, 0, 0);
      }
    }
    // + x_pre, activation (wave 2 = tanh, others sigmoid), exchange via LDS
#pragma unroll
    for (int mt = 0; mt < 2; mt++) {
      f32x4 a = mt ? acc1 : acc0;
#pragma unroll
      for (int r = 0; r < 4; r++) {
        float v = a[r] + xv[mt * 4 + r];
        float act = (w == 2) ? tanh_f(v) : sigm_f(v);
        gbuf[w][col][(lane >> 4) * 4 + r + mt * 16] = act;
      }
    }
    __syncthreads();
    // cell update: 512 cells (j,b) over 256 threads
#pragma unroll
    for (int q = 0; q < 2; q++) {
      int cell = tid + q * 256;
      int j = cell >> 5, b = cell & 31;
      float iv = gbuf[0][j][b], fv = gbuf[1][j][b], gv = gbuf[2][j][b], ov = gbuf[3][j][b];
      float c = fv * cl[cell] + iv * gv;
      cl[cell] = c;
      float h = ov * tanh_f(c);
      u16 hi = f2bf(h);
      u16 lo = f2bf(h - bf2f(hi));
      size_t rr = (size_t)((b << 10) | t);
      outb[rr * 1024 + base + j] = hi;
      outb[rr * 1024 + 512 + base + j] = lo;
      int kb = (base + j) * 2;
      int sw = b * 1024 + (kb ^ ((b & 7) << 4));
      char* hb2 = (char*)hbuf + (size_t)((t + 1) & 1) * 65536;
      *(u16*)(hb2 + sw) = hi;
      *(u16*)(hb2 + 32768 + sw) = lo;
    }
    __syncthreads();
    __threadfence();  // release
    if (tid == 0)
      __hip_atomic_store(&flags[wg], (unsigned)(t + 1), __ATOMIC_RELEASE, __HIP_MEMORY_SCOPE_AGENT);
  }
}

// ---------------- attention score reduction: att = tanh(T + mlp_b) @ sim_W ----------------
__global__ void att2_kernel(const float* __restrict__ T, const float* __restrict__ mlp_b,
                            const float* __restrict__ simW, float* __restrict__ att) {
  int r = blockIdx.x * 256 + threadIdx.x;  // 32768
  float s = 0.f;
  for (int a = 0; a < 80; a++)
    s += simW[a] * tanh_f(T[(size_t)r * 128 + a] + mlp_b[a]);
  att[r] = s;
}

// ---------------- online-softmax prefix scan + exclusive cumsum + fc-A build ----------------
// outb row r: [out_hi(512) | out_lo(512)]. Afc row r: [cum_hi | out_hi | cum_lo | out_lo].
__global__ __launch_bounds__(512) void scan_kernel(
    const float* __restrict__ att, const u16* __restrict__ outb, u16* __restrict__ Afc)
{
  int b = blockIdx.x;
  int h = threadIdx.x;
  float m = -__builtin_inff(), Z = 0.f, S = 0.f, C = 0.f;
  for (int t = 0; t < 1024; t++) {
    float a = att[(b << 10) + t];
    size_t r = (size_t)((b << 10) + t);
    u16 ohi = outb[r * 1024 + h];
    u16 olo = outb[r * 1024 + 512 + h];
    float ov = bf2f(ohi) + bf2f(olo);
    float nm = fmaxf(m, a);             // branchless online softmax (uniform across block)
    float sc = __expf(m - nm);
    float wgt = __expf(a - nm);
    Z = Z * sc + wgt;
    S = S * sc + wgt * ov;
    m = nm;
    float ao = S / Z;
    u16 chi = f2bf(C);
    u16* row = Afc + r * 2048;
    row[h] = chi;
    row[512 + h] = ohi;
    row[1024 + h] = f2bf(C - bf2f(chi));
    row[1536 + h] = olo;
    C += ao;  // exclusive prefix: wrote C before adding attn_out(t)
  }
}

// ---------------- launch ----------------
extern "C" void kernel_launch(void* const* d_in, const int* in_sizes, int n_in,
                              void* d_out, int out_size, void* d_ws, size_t ws_size,
                              hipStream_t stream) {
  (void)in_sizes; (void)n_in; (void)out_size; (void)ws_size;
  const int* skill = (const int*)d_in[0];
  const int* answer = (const int*)d_in[1];
  const float* skill_table = (const float*)d_in[2];
  const float* answer_table = (const float*)d_in[3];
  const float* W_ih = (const float*)d_in[4];
  const float* W_hh = (const float*)d_in[5];
  const float* b_ih = (const float*)d_in[6];
  const float* b_hh = (const float*)d_in[7];
  const float* mlp_W = (const float*)d_in[8];
  const float* mlp_b = (const float*)d_in[9];
  const float* sim_W = (const float*)d_in[10];
  const float* fc_W = (const float*)d_in[11];
  const float* fc_b = (const float*)d_in[12];
  float* out = (float*)d_out;

  char* ws = (char*)d_ws;
  size_t o = 0;
  auto alloc = [&](size_t b) { size_t r = o; o += (b + 255) & ~(size_t)255; return r; };
  u16* Wihcat = (u16*)(ws + alloc((size_t)2048 * 1536 * 2));
  u16* Whhcat = (u16*)(ws + alloc((size_t)2048 * 1024 * 2));
  u16* Mlpcat = (u16*)(ws + alloc((size_t)128 * 1536 * 2));
  u16* Wcat = (u16*)(ws + alloc((size_t)1024 * 3072 * 2));
  char* hregion = ws + alloc(131072 + 512);
  u16* hbuf = (u16*)hregion;
  unsigned* flags = (unsigned*)(hregion + 131072);
  float* att = (float*)(ws + alloc((size_t)32768 * 4));
  // region2: saecat (embed->gemm0), then reused as outb (lstm->...)
  char* reg2 = ws + alloc((size_t)32768 * 1024 * 2);
  u16* saecat = (u16*)reg2;
  u16* outb = (u16*)reg2;
  // region1: xpre fp32 (gemm0->lstm), then reused as T (gemm1->att2) then Afc (scan->gemm2)
  char* reg1 = ws + alloc((size_t)32768 * 2048 * 4);
  float* xpre = (float*)reg1;
  float* T = (float*)reg1;
  u16* Afc = (u16*)reg1;

  wih_prep_kernel<<<12288, 256, 0, stream>>>(W_ih, Wihcat);
  whh_prep_kernel<<<8192, 256, 0, stream>>>(W_hh, Whhcat);
  mlp_prep_kernel<<<768, 256, 0, stream>>>(mlp_W, Mlpcat);
  fc_prep_kernel<<<12288, 256, 0, stream>>>(fc_W, Wcat);
  embed_kernel<<<32768, 256, 0, stream>>>(skill, answer, skill_table, answer_table, saecat);
  // x_pre = sae @ W_ih^T + (b_ih+b_hh), 3-term split (virtual K=1536), stored (L,B,2048) FP32
  gemm_bt<0><<<4096, 256, 0, stream>>>(saecat, Wihcat, b_ih, b_hh, xpre, 2048, 1536, 1024, 1536, 1024);
  hipMemsetAsync(hregion, 0, 131072 + 512, stream);  // h(−1)=0 and flags=0 every launch
  lstm_kernel<<<32, 256, 0, stream>>>(xpre, Whhcat, outb, hbuf, flags);
  // T = out @ mlp_W^T  (fp32, padded N=128), 3-term split (virtual K=1536)
  gemm_bt<1><<<256, 256, 0, stream>>>(outb, Mlpcat, nullptr, nullptr, T, 128, 1536, 1024, 1536, 1024);
  att2_kernel<<<128, 256, 0, stream>>>(T, mlp_b, sim_W, att);
  scan_kernel<<<32, 512, 0, stream>>>(att, outb, Afc);
  // res = sigmoid([cum,out] @ fc_W^T + fc_b), 3-term split-bf16 (virtual K=3072)
  gemm_bt<2><<<2048, 256, 0, stream>>>(Afc, Wcat, fc_b, nullptr, out, 1024, 3072, 2048, 3072, 2048);
}

// Round 5
// 7077.206 us; speedup vs baseline: 1.8735x; 1.8735x over previous
//
#include <hip/hip_runtime.h>
#include <cstdint>
#include <cstddef>

using u16 = unsigned short;
typedef __attribute__((ext_vector_type(8))) short short8;
typedef __attribute__((ext_vector_type(4))) float f32x4;

__device__ __forceinline__ float bf2f(u16 u) {
  unsigned int i = ((unsigned int)u) << 16;
  float f; __builtin_memcpy(&f, &i, 4); return f;
}
__device__ __forceinline__ u16 f2bf(float f) {
  unsigned int i; __builtin_memcpy(&i, &f, 4);
  unsigned int r = (i + 0x7FFFu + ((i >> 16) & 1u)) >> 16;
  return (u16)r;
}
__device__ __forceinline__ float sigm_f(float x) { return 1.f / (1.f + __expf(-x)); }
__device__ __forceinline__ float tanh_f(float x) {
  float cx = fminf(10.f, fmaxf(-10.f, x));
  float e = __expf(2.f * cx);
  return (e - 1.f) / (e + 1.f);
}

// ---------------- prep kernels ----------------
// W_ih (2048x512) -> Wihcat (2048x1536) bf16 = [hi | hi | lo]
__global__ void wih_prep_kernel(const float* __restrict__ W, u16* __restrict__ dst) {
  int i = blockIdx.x * 256 + threadIdx.x;  // 2048*1536
  int r = i / 1536, k = i - r * 1536;
  u16 v;
  if (k < 1024) {
    int kk = (k < 512) ? k : (k - 512);
    v = f2bf(W[(size_t)r * 512 + kk]);
  } else {
    float x = W[(size_t)r * 512 + (k - 1024)];
    u16 hi = f2bf(x);
    v = f2bf(x - bf2f(hi));
  }
  dst[i] = v;
}

// W_hh (2048x512) -> Whhcat (2048x1024) bf16 = [hi | lo]
__global__ void whh_prep_kernel(const float* __restrict__ W, u16* __restrict__ dst) {
  int i = blockIdx.x * 256 + threadIdx.x;  // 2048*1024
  int r = i >> 10, k = i & 1023;
  u16 v;
  if (k < 512) v = f2bf(W[(size_t)r * 512 + k]);
  else {
    float x = W[(size_t)r * 512 + (k - 512)];
    u16 hi = f2bf(x);
    v = f2bf(x - bf2f(hi));
  }
  dst[i] = v;
}

// mlp_W (80x512) -> Mlpcat (128x1536) bf16 = [Whi | Whi | Wlo], rows>=80 zero
__global__ void mlp_prep_kernel(const float* __restrict__ mlpW, u16* __restrict__ dst) {
  int i = blockIdx.x * 256 + threadIdx.x;  // 128*1536
  int r = i / 1536, k = i - r * 1536;
  u16 v = 0;
  if (r < 80) {
    if (k < 1024) {
      int kk = (k < 512) ? k : (k - 512);
      v = f2bf(mlpW[r * 512 + kk]);
    } else {
      float x = mlpW[r * 512 + (k - 1024)];
      u16 hi = f2bf(x);
      v = f2bf(x - bf2f(hi));
    }
  }
  dst[i] = v;
}

// fc_W (1000x1024) -> Wcat (1024 x 3072) bf16 = [Whi | Whi | Wlo], rows >=1000 zero
__global__ void fc_prep_kernel(const float* __restrict__ fcW, u16* __restrict__ dst) {
  int i = blockIdx.x * 256 + threadIdx.x;  // 1024*3072
  int n = i / 3072, k = i - n * 3072;
  u16 v = 0;
  if (n < 1000) {
    if (k < 2048) {
      int kk = (k < 1024) ? k : (k - 1024);
      v = f2bf(fcW[(size_t)n * 1024 + kk]);
    } else {
      float x = fcW[(size_t)n * 1024 + (k - 2048)];
      u16 hi = f2bf(x);
      v = f2bf(x - bf2f(hi));
    }
  }
  dst[i] = v;
}

// embeddings -> saecat split bf16 (32768 x 1024) = [sae_hi(512) | sae_lo(512)]
__global__ void embed_kernel(const int* __restrict__ skill, const int* __restrict__ answer,
                             const float* __restrict__ st, const float* __restrict__ at,
                             u16* __restrict__ saecat) {
  int r = blockIdx.x;
  int s = skill[r], a = answer[r];
  const float* se = st + (size_t)s * 256;
  const float* ae = at + (size_t)a * 256;
  u16* dst = saecat + (size_t)r * 1024;
  int c = threadIdx.x;  // 0..255
  bool one = (a == 1);
  float v0 = one ? se[c] : ae[c];
  float v1 = one ? ae[c] : se[c];
  u16 h0 = f2bf(v0), h1 = f2bf(v1);
  dst[c] = h0;
  dst[c + 256] = h1;
  dst[512 + c] = f2bf(v0 - bf2f(h0));
  dst[768 + c] = f2bf(v1 - bf2f(h1));
}

// ---------------- generic bf16 MFMA GEMM: C = A(MxK) * Bw(NxK)^T ----------------
// Virtual-K: A column = (k >= kwrap) ? k - kwrap : k  (B always reads k directly).
// amapA: logical A-row r -> phys ((r&1023)<<5) + (r>>10)   (outb [t][b] layout)
// MODE 0: x_pre: +(b_ih+b_hh), store FP32 x_pre[(t*32+b)*2048+col], row=(b<<10|t)
// MODE 1: att1:  store fp32 T[row*128+col]
// MODE 2: fc:    +fc_b, sigmoid, store fp32 d_out[row*1000+col] (col<1000)
template <int MODE>
__global__ __launch_bounds__(256) void gemm_bt(
    const u16* __restrict__ A, const u16* __restrict__ Bw,
    const float* __restrict__ bias0, const float* __restrict__ bias1,
    void* __restrict__ Cout, int N, int K, int lda, int ldb, int kwrap, int amapA)
{
  __shared__ u16 As[128][40];
  __shared__ u16 Bs[128][40];
  const int ntn = N >> 7;
  const int tm = blockIdx.x / ntn;
  const int tn = blockIdx.x - tm * ntn;
  const int r0 = tm << 7, c0 = tn << 7;
  const int tid = threadIdx.x;
  const int lane = tid & 63, w = tid >> 6;
  const int wr = (w >> 1) << 6, wc = (w & 1) << 6;
  const int sr = tid >> 2, sk = (tid & 3) << 3;
  const int fr = lane & 15, fk = (lane >> 4) << 3;
  f32x4 zero = {0.f, 0.f, 0.f, 0.f};
  f32x4 acc[4][4];
#pragma unroll
  for (int i = 0; i < 4; i++)
#pragma unroll
    for (int j = 0; j < 4; j++) acc[i][j] = zero;

  int ra = r0 + sr, rb = r0 + sr + 64;
  if (amapA) {
    ra = ((ra & 1023) << 5) + (ra >> 10);
    rb = ((rb & 1023) << 5) + (rb >> 10);
  }

  for (int k0 = 0; k0 < K; k0 += 32) {
    int ka = (k0 >= kwrap) ? (k0 - kwrap) : k0;
    const u16* Bp = Bw + (size_t)(c0 + sr) * ldb + k0 + sk;
    *(short8*)(&As[sr][sk])      = *(const short8*)(A + (size_t)ra * lda + ka + sk);
    *(short8*)(&As[sr + 64][sk]) = *(const short8*)(A + (size_t)rb * lda + ka + sk);
    *(short8*)(&Bs[sr][sk])      = *(const short8*)(Bp);
    *(short8*)(&Bs[sr + 64][sk]) = *(const short8*)(Bp + (size_t)64 * ldb);
    __syncthreads();
    short8 af[4], bfv[4];
#pragma unroll
    for (int i = 0; i < 4; i++) af[i] = *(const short8*)(&As[wr + i * 16 + fr][fk]);
#pragma unroll
    for (int i = 0; i < 4; i++) bfv[i] = *(const short8*)(&Bs[wc + i * 16 + fr][fk]);
#pragma unroll
    for (int mi = 0; mi < 4; mi++)
#pragma unroll
      for (int ni = 0; ni < 4; ni++)
        acc[mi][ni] = __builtin_amdgcn_mfma_f32_16x16x32_bf16(af[mi], bfv[ni], acc[mi][ni], 0, 0, 0);
    __syncthreads();
  }

  const int cr = (lane >> 4) << 2, cc = lane & 15;
  if constexpr (MODE == 0) {
    float* xp = (float*)Cout;
#pragma unroll
    for (int ni = 0; ni < 4; ni++) {
      int col = c0 + wc + ni * 16 + cc;
      float bs = bias0[col] + bias1[col];
#pragma unroll
      for (int mi = 0; mi < 4; mi++)
#pragma unroll
        for (int r = 0; r < 4; r++) {
          int row = r0 + wr + mi * 16 + cr + r;
          int t = row & 1023, b = row >> 10;
          xp[(size_t)(t * 32 + b) * 2048 + col] = acc[mi][ni][r] + bs;
        }
    }
  } else if constexpr (MODE == 1) {
    float* T = (float*)Cout;
#pragma unroll
    for (int ni = 0; ni < 4; ni++) {
      int col = c0 + wc + ni * 16 + cc;
#pragma unroll
      for (int mi = 0; mi < 4; mi++)
#pragma unroll
        for (int r = 0; r < 4; r++) {
          int row = r0 + wr + mi * 16 + cr + r;
          T[(size_t)row * 128 + col] = acc[mi][ni][r];
        }
    }
  } else {
    float* op = (float*)Cout;
#pragma unroll
    for (int ni = 0; ni < 4; ni++) {
      int col = c0 + wc + ni * 16 + cc;
      if (col < 1000) {
        float bs = bias0[col];
#pragma unroll
        for (int mi = 0; mi < 4; mi++)
#pragma unroll
          for (int r = 0; r < 4; r++) {
            int row = r0 + wr + mi * 16 + cr + r;
            op[(size_t)row * 1000 + col] = sigm_f(acc[mi][ni][r] + bs);
          }
      }
    }
  }
}

// ---------------- persistent LSTM (16 wgs x 512 thr, split-bf16 h/W_hh, fp32 x_pre) ----------------
// wg owns hidden cols [wg*32, wg*32+32). wave w: gate g=w>>1, col-half colh=(w&1)*16.
// h published hi+lo bf16, double-buffered hbuf[2][2][32][512], PRE-SWIZZLED:
//   byte(b,k) = buf*65536 + plane*32768 + b*1024 + ((2k) ^ ((b&7)<<4))
// (XOR preserves 64B-run contiguity -> writer stores are coalesced 64B runs.)
// flags padded 128B apart; wave0-only poll; wave0/tid0-only fences.
// outb [t][b] layout (row t*32+b), written AFTER flag publication (off critical path).
__global__ __launch_bounds__(512) void lstm_kernel(
    const float* __restrict__ xpre, const u16* __restrict__ Whh,
    u16* __restrict__ outb, u16* __restrict__ hbuf, unsigned* __restrict__ flags)
{
  __shared__ u16 hl[32768];           // 64 KB: h(t-1) hi (32KB) + lo (32KB), swizzled
  __shared__ float gbuf[4][32][33];   // gate exchange (pad 33 -> conflict-free)
  __shared__ float cl[1024];          // cell state c (fp32, resident)
  const int tid = threadIdx.x;
  const int lane = tid & 63, w = tid >> 6;   // w 0..7
  const int wg = blockIdx.x;                 // 0..15
  const int base = wg << 5;                  // 32 cols per wg
  const int g = w >> 1;                      // gate 0..3 (i,f,g,o)
  const int colh = (w & 1) << 4;             // 0 | 16
  const int col = lane & 15;
  const int kofs = (lane >> 4) << 3;

  short8 whi[16], wlo[16];  // W_hh fragments (hi+lo), resident all 1024 steps
  {
    const u16* wp = Whh + (size_t)(g * 512 + base + colh + col) * 1024 + kofs;
#pragma unroll
    for (int kt = 0; kt < 16; kt++) {
      whi[kt] = *(const short8*)(wp + kt * 32);
      wlo[kt] = *(const short8*)(wp + 512 + kt * 32);
    }
  }
  cl[tid] = 0.f; cl[tid + 512] = 0.f;
  __syncthreads();

  for (int t = 0; t < 1024; t++) {
    // prefetch x_pre gate slice (independent of the sync)
    float xv[8];
    {
      const float* xp = xpre + (size_t)t * 32 * 2048 + (g * 512 + base + colh + col);
#pragma unroll
      for (int mt = 0; mt < 2; mt++)
#pragma unroll
        for (int r = 0; r < 4; r++) {
          int b = (lane >> 4) * 4 + r + mt * 16;
          xv[mt * 4 + r] = xp[(size_t)b * 2048];
        }
    }
    // wait for all wgs to have published h(t-1): wave 0 polls, then one fence
    if (t > 0) {
      if (w == 0) {
        for (;;) {
          unsigned v = 0xFFFFFFFFu;
          if (lane < 16) v = __hip_atomic_load(&flags[lane << 5], __ATOMIC_RELAXED, __HIP_MEMORY_SCOPE_AGENT);
          if (!(~__ballot(v >= (unsigned)t))) break;
          __builtin_amdgcn_s_sleep(1);
        }
        __threadfence();  // acquire: wb+inv covers this CU/XCD for all waves
      }
      __syncthreads();
    }
    // stage h(t-1) hi+lo to LDS (64 KB, coalesced b128)
    {
      const short8* hs = (const short8*)(hbuf + (size_t)(t & 1) * 32768);
      short8* hd = (short8*)hl;
#pragma unroll
      for (int i = 0; i < 8; i++) hd[i * 512 + tid] = hs[i * 512 + tid];
    }
    __syncthreads();
    // gates = h @ Whh_slice^T  (M=32 batches, N=16 cols, K=512, 3-term split)
    f32x4 acc0 = {0.f,0.f,0.f,0.f}, acc1 = {0.f,0.f,0.f,0.f};
    {
      const char* hb = (const char*)hl;
#pragma unroll
      for (int kt = 0; kt < 16; kt++) {
        int kbyte = (kt * 32 + kofs) * 2;
        int b0 = col, b1 = col + 16;
        int o0 = b0 * 1024 + (kbyte ^ ((b0 & 7) << 4));
        int o1 = b1 * 1024 + (kbyte ^ ((b1 & 7) << 4));
        short8 a0 = *(const short8*)(hb + o0);
        short8 a1 = *(const short8*)(hb + o1);
        short8 l0 = *(const short8*)(hb + 32768 + o0);
        short8 l1 = *(const short8*)(hb + 32768 + o1);
        acc0 = __builtin_amdgcn_mfma_f32_16x16x32_bf16(a0, whi[kt], acc0, 0, 0, 0);
        acc1 = __builtin_amdgcn_mfma_f32_16x16x32_bf16(a1, whi[kt], acc1, 0, 0, 0);
        acc0 = __builtin_amdgcn_mfma_f32_16x16x32_bf16(l0, whi[kt], acc0, 0, 0, 0);
        acc1 = __builtin_amdgcn_mfma_f32_16x16x32_bf16(l1, whi[kt], acc1, 0, 0, 0);
        acc0 = __builtin_amdgcn_mfma_f32_16x16x32_bf16(a0, wlo[kt], acc0, 0, 0, 0);
        acc1 = __builtin_amdgcn_mfma_f32_16x16x32_bf16(a1, wlo[kt], acc1, 0, 0, 0);
      }
    }
    // + x_pre, activation (gate 2 = tanh, others sigmoid), exchange via LDS
#pragma unroll
    for (int mt = 0; mt < 2; mt++) {
      f32x4 a = mt ? acc1 : acc0;
#pragma unroll
      for (int r = 0; r < 4; r++) {
        float v = a[r] + xv[mt * 4 + r];
        float act = (g == 2) ? tanh_f(v) : sigm_f(v);
        gbuf[g][colh + col][(lane >> 4) * 4 + r + mt * 16] = act;
      }
    }
    __syncthreads();
    // cell update: 1024 cells over 512 threads; j-fastest -> coalesced 64B publication runs
    u16 hiv[2], lov[2];
#pragma unroll
    for (int p = 0; p < 2; p++) {
      int cell = p * 512 + tid;
      int j = cell & 31, b = cell >> 5;
      float iv = gbuf[0][j][b], fv = gbuf[1][j][b], gv = gbuf[2][j][b], ov = gbuf[3][j][b];
      float c = fv * cl[cell] + iv * gv;
      cl[cell] = c;
      float h = ov * tanh_f(c);
      u16 hi = f2bf(h);
      u16 lo = f2bf(h - bf2f(hi));
      hiv[p] = hi; lov[p] = lo;
      int kb = (base + j) * 2;
      int sw = b * 1024 + (kb ^ ((b & 7) << 4));
      char* hb2 = (char*)hbuf + (size_t)((t + 1) & 1) * 65536;
      *(u16*)(hb2 + sw) = hi;
      *(u16*)(hb2 + 32768 + sw) = lo;
    }
    __syncthreads();  // drains all waves' hbuf stores into L2
    if (tid == 0) {
      __threadfence();  // release: one wbl2 flushes the wg's stores
      __hip_atomic_store(&flags[wg << 5], (unsigned)(t + 1), __ATOMIC_RELAXED, __HIP_MEMORY_SCOPE_AGENT);
    }
    // outb stores off the critical path (next kernel syncs at boundary)
#pragma unroll
    for (int p = 0; p < 2; p++) {
      int cell = p * 512 + tid;
      int j = cell & 31, b = cell >> 5;
      size_t row = (size_t)((t << 5) + b);
      outb[row * 1024 + base + j] = hiv[p];
      outb[row * 1024 + 512 + base + j] = lov[p];
    }
  }
}

// ---------------- attention score reduction: att = tanh(T + mlp_b) @ sim_W ----------------
__global__ void att2_kernel(const float* __restrict__ T, const float* __restrict__ mlp_b,
                            const float* __restrict__ simW, float* __restrict__ att) {
  int r = blockIdx.x * 256 + threadIdx.x;  // 32768
  float s = 0.f;
  for (int a = 0; a < 80; a++)
    s += simW[a] * tanh_f(T[(size_t)r * 128 + a] + mlp_b[a]);
  att[r] = s;
}

// ---------------- online-softmax prefix scan + exclusive cumsum + fc-A build ----------------
// outb phys row = t*32+b: [out_hi(512) | out_lo(512)]. Afc logical row r=(b<<10|t).
__global__ __launch_bounds__(512) void scan_kernel(
    const float* __restrict__ att, const u16* __restrict__ outb, u16* __restrict__ Afc)
{
  int b = blockIdx.x;
  int h = threadIdx.x;
  float m = -__builtin_inff(), Z = 0.f, S = 0.f, C = 0.f;
  for (int t = 0; t < 1024; t++) {
    float a = att[(b << 10) + t];
    size_t rl = (size_t)((b << 10) + t);      // logical row (Afc)
    size_t rp = (size_t)((t << 5) + b);       // phys row (outb)
    u16 ohi = outb[rp * 1024 + h];
    u16 olo = outb[rp * 1024 + 512 + h];
    float ov = bf2f(ohi) + bf2f(olo);
    float nm = fmaxf(m, a);
    float sc = __expf(m - nm);
    float wgt = __expf(a - nm);
    Z = Z * sc + wgt;
    S = S * sc + wgt * ov;
    m = nm;
    float ao = S / Z;
    u16 chi = f2bf(C);
    u16* row = Afc + rl * 2048;
    row[h] = chi;
    row[512 + h] = ohi;
    row[1024 + h] = f2bf(C - bf2f(chi));
    row[1536 + h] = olo;
    C += ao;  // exclusive prefix
  }
}

// ---------------- launch ----------------
extern "C" void kernel_launch(void* const* d_in, const int* in_sizes, int n_in,
                              void* d_out, int out_size, void* d_ws, size_t ws_size,
                              hipStream_t stream) {
  (void)in_sizes; (void)n_in; (void)out_size; (void)ws_size;
  const int* skill = (const int*)d_in[0];
  const int* answer = (const int*)d_in[1];
  const float* skill_table = (const float*)d_in[2];
  const float* answer_table = (const float*)d_in[3];
  const float* W_ih = (const float*)d_in[4];
  const float* W_hh = (const float*)d_in[5];
  const float* b_ih = (const float*)d_in[6];
  const float* b_hh = (const float*)d_in[7];
  const float* mlp_W = (const float*)d_in[8];
  const float* mlp_b = (const float*)d_in[9];
  const float* sim_W = (const float*)d_in[10];
  const float* fc_W = (const float*)d_in[11];
  const float* fc_b = (const float*)d_in[12];
  float* out = (float*)d_out;

  char* ws = (char*)d_ws;
  size_t o = 0;
  auto alloc = [&](size_t b) { size_t r = o; o += (b + 255) & ~(size_t)255; return r; };
  u16* Wihcat = (u16*)(ws + alloc((size_t)2048 * 1536 * 2));
  u16* Whhcat = (u16*)(ws + alloc((size_t)2048 * 1024 * 2));
  u16* Mlpcat = (u16*)(ws + alloc((size_t)128 * 1536 * 2));
  u16* Wcat = (u16*)(ws + alloc((size_t)1024 * 3072 * 2));
  char* hregion = ws + alloc(131072 + 2048);
  u16* hbuf = (u16*)hregion;
  unsigned* flags = (unsigned*)(hregion + 131072);
  float* att = (float*)(ws + alloc((size_t)32768 * 4));
  // region2: saecat (embed->gemm0), then reused as outb (lstm->...)
  char* reg2 = ws + alloc((size_t)32768 * 1024 * 2);
  u16* saecat = (u16*)reg2;
  u16* outb = (u16*)reg2;
  // region1: xpre fp32 (gemm0->lstm), then reused as T (gemm1->att2) then Afc (scan->gemm2)
  char* reg1 = ws + alloc((size_t)32768 * 2048 * 4);
  float* xpre = (float*)reg1;
  float* T = (float*)reg1;
  u16* Afc = (u16*)reg1;

  wih_prep_kernel<<<12288, 256, 0, stream>>>(W_ih, Wihcat);
  whh_prep_kernel<<<8192, 256, 0, stream>>>(W_hh, Whhcat);
  mlp_prep_kernel<<<768, 256, 0, stream>>>(mlp_W, Mlpcat);
  fc_prep_kernel<<<12288, 256, 0, stream>>>(fc_W, Wcat);
  embed_kernel<<<32768, 256, 0, stream>>>(skill, answer, skill_table, answer_table, saecat);
  // x_pre = sae @ W_ih^T + (b_ih+b_hh), 3-term split (virtual K=1536), stored (L,B,2048) FP32
  gemm_bt<0><<<4096, 256, 0, stream>>>(saecat, Wihcat, b_ih, b_hh, xpre, 2048, 1536, 1024, 1536, 1024, 0);
  hipMemsetAsync(hregion, 0, 131072 + 2048, stream);  // h(−1)=0 and flags=0 every launch
  lstm_kernel<<<16, 512, 0, stream>>>(xpre, Whhcat, outb, hbuf, flags);
  // T = out @ mlp_W^T  (fp32, padded N=128), 3-term split (virtual K=1536), A row-remapped
  gemm_bt<1><<<256, 256, 0, stream>>>(outb, Mlpcat, nullptr, nullptr, T, 128, 1536, 1024, 1536, 1024, 1);
  att2_kernel<<<128, 256, 0, stream>>>(T, mlp_b, sim_W, att);
  scan_kernel<<<32, 512, 0, stream>>>(att, outb, Afc);
  // res = sigmoid([cum,out] @ fc_W^T + fc_b), 3-term split-bf16 (virtual K=3072)
  gemm_bt<2><<<2048, 256, 0, stream>>>(Afc, Wcat, fc_b, nullptr, out, 1024, 3072, 2048, 3072, 2048, 0);
}